// Round 1
// baseline (1929.403 us; speedup 1.0000x reference)
//
#include <hip/hip_runtime.h>
#include <cstdint>
#include <cstddef>

#define N_NODES 204800
#define N_EDGES 3276800
#define NB 2048
#define NR 100
#define NC 64
#define NH 256

// ---------------- graph preprocessing ----------------

__global__ void k_count(const int* __restrict__ ei, int* __restrict__ cnt) {
    int e = blockIdx.x * 256 + threadIdx.x;
    atomicAdd(&cnt[ei[N_EDGES + e]], 1);
}

__global__ void k_dinv(const int* __restrict__ cnt, float* __restrict__ dinv) {
    int i = blockIdx.x * 256 + threadIdx.x;
    dinv[i] = rsqrtf((float)(cnt[i] + 1));   // +1 self loop
}

__global__ void k_scan1(const int* __restrict__ cnt, int* __restrict__ offs,
                        int* __restrict__ bsum) {
    __shared__ int tmp[512];
    int t = threadIdx.x;
    int idx = blockIdx.x * 512 + t;
    int v = cnt[idx];
    tmp[t] = v;
    __syncthreads();
    for (int off = 1; off < 512; off <<= 1) {
        int x = 0;
        if (t >= off) x = tmp[t - off];
        __syncthreads();
        tmp[t] += x;
        __syncthreads();
    }
    offs[idx] = tmp[t] - v;                 // exclusive
    if (t == 511) bsum[blockIdx.x] = tmp[511];
}

__global__ void k_scan2(int* __restrict__ bsum) {
    __shared__ int tmp[512];
    int t = threadIdx.x;
    int v = (t < 400) ? bsum[t] : 0;
    tmp[t] = v;
    __syncthreads();
    for (int off = 1; off < 512; off <<= 1) {
        int x = 0;
        if (t >= off) x = tmp[t - off];
        __syncthreads();
        tmp[t] += x;
        __syncthreads();
    }
    if (t < 400) bsum[t] = tmp[t] - v;      // exclusive block bases
}

__global__ void k_scan3(int* __restrict__ offs, const int* __restrict__ bsum,
                        int* __restrict__ cursor) {
    int t = threadIdx.x;
    int idx = blockIdx.x * 512 + t;
    int o = offs[idx] + bsum[blockIdx.x];
    offs[idx] = o;
    cursor[idx] = o;
}

__global__ void k_scatter(const int* __restrict__ ei, int* __restrict__ cursor,
                          int* __restrict__ csr) {
    int e = blockIdx.x * 256 + threadIdx.x;
    int s = ei[e];
    int d = ei[N_EDGES + e];
    int p = atomicAdd(&cursor[d], 1);
    csr[p] = s;
}

// sstate[i][c] = dinv[i] * state[i][c]
__global__ void k_sstate(const float* __restrict__ state, const float* __restrict__ dinv,
                         float* __restrict__ ss) {
    int idx = blockIdx.x * 256 + threadIdx.x;     // float4 index
    int row = idx >> 4;                            // 16 float4 per row
    float4 v = reinterpret_cast<const float4*>(state)[idx];
    float d = dinv[row];
    v.x *= d; v.y *= d; v.z *= d; v.w *= d;
    reinterpret_cast<float4*>(ss)[idx] = v;
}

// ---------------- GCN gather + 64x64 GEMM + relu + residual ----------------
// one wave per node row; lane = channel
__global__ __launch_bounds__(256) void k_gcn(
    const float* __restrict__ ss, const float* __restrict__ state,
    const int* __restrict__ csr, const int* __restrict__ offs,
    const int* __restrict__ cnt, const float* __restrict__ dinv,
    const float* __restrict__ Wg, const float* __restrict__ bg,
    float* __restrict__ xres) {
    __shared__ float Wl[64 * 64];
    __shared__ float av[4][64];
    int tid = threadIdx.x;
    for (int i = tid; i < 1024; i += 256)
        reinterpret_cast<float4*>(Wl)[i] = reinterpret_cast<const float4*>(Wg)[i];

    int wave = tid >> 6, lane = tid & 63;
    int row = blockIdx.x * 4 + wave;

    float di = dinv[row];
    float st = state[(size_t)row * 64 + lane];
    float a0 = ss[(size_t)row * 64 + lane];      // self loop: dinv[row]*state[row]
    float a1 = 0.f, a2 = 0.f, a3 = 0.f;
    int s0 = offs[row], c = cnt[row];
    int e = 0;
    for (; e + 4 <= c; e += 4) {
        int sa = csr[s0 + e + 0];
        int sb = csr[s0 + e + 1];
        int sc = csr[s0 + e + 2];
        int sd = csr[s0 + e + 3];
        a0 += ss[(size_t)sa * 64 + lane];
        a1 += ss[(size_t)sb * 64 + lane];
        a2 += ss[(size_t)sc * 64 + lane];
        a3 += ss[(size_t)sd * 64 + lane];
    }
    for (; e < c; ++e) a0 += ss[(size_t)csr[s0 + e] * 64 + lane];
    float a = ((a0 + a1) + (a2 + a3)) * di;

    __syncthreads();            // Wl ready
    av[wave][lane] = a;
    __syncthreads();            // av ready

    float r = bg[lane];
    #pragma unroll
    for (int c4 = 0; c4 < 64; c4 += 4) {
        float4 a4 = *reinterpret_cast<const float4*>(&av[wave][c4]);
        r += a4.x * Wl[(c4 + 0) * 64 + lane];
        r += a4.y * Wl[(c4 + 1) * 64 + lane];
        r += a4.z * Wl[(c4 + 2) * 64 + lane];
        r += a4.w * Wl[(c4 + 3) * 64 + lane];
    }
    xres[(size_t)row * 64 + lane] = fmaxf(r, 0.f) + st;
}

// ---------------- fused MLP: layer1 -> LDS -> layer2 -> pool -> dot ----------------
// one block per half graph (50 rows); 256 threads, thread j = hidden unit
__global__ __launch_bounds__(256) void k_mlp(
    const float* __restrict__ xres, const float* __restrict__ action,
    const float* __restrict__ W1, const float* __restrict__ b1,
    const float* __restrict__ W2, const float* __restrict__ b2,
    const float* __restrict__ W3, const float* __restrict__ b3,
    float* __restrict__ out) {
    __shared__ float h1s[50][256];   // 51200 B
    __shared__ float red[256];
    int b = blockIdx.x >> 1;
    int half = blockIdx.x & 1;
    int j = threadIdx.x;
    const float* xb = xres + (size_t)b * NR * NC + (size_t)half * 50 * NC;
    const float* ab = action + (size_t)b * NR * NR + (size_t)half * 50 * NR;

    float bj1 = b1[j];
    for (int g = 0; g < 2; ++g) {
        int r0 = g * 25;
        float acc[25];
        #pragma unroll
        for (int i = 0; i < 25; i++) acc[i] = bj1;
        for (int k = 0; k < NC; k += 4) {
            float w0 = W1[(k + 0) * NH + j];
            float w1 = W1[(k + 1) * NH + j];
            float w2 = W1[(k + 2) * NH + j];
            float w3 = W1[(k + 3) * NH + j];
            #pragma unroll
            for (int i = 0; i < 25; i++) {
                float4 c4 = *reinterpret_cast<const float4*>(&xb[(r0 + i) * NC + k]);
                acc[i] += c4.x * w0 + c4.y * w1 + c4.z * w2 + c4.w * w3;
            }
        }
        for (int k = 0; k < NR; k += 4) {
            float w0 = W1[(NC + k + 0) * NH + j];
            float w1 = W1[(NC + k + 1) * NH + j];
            float w2 = W1[(NC + k + 2) * NH + j];
            float w3 = W1[(NC + k + 3) * NH + j];
            #pragma unroll
            for (int i = 0; i < 25; i++) {
                float4 c4 = *reinterpret_cast<const float4*>(&ab[(r0 + i) * NR + k]);
                acc[i] += c4.x * w0 + c4.y * w1 + c4.z * w2 + c4.w * w3;
            }
        }
        #pragma unroll
        for (int i = 0; i < 25; i++) h1s[r0 + i][j] = fmaxf(acc[i], 0.f);
    }
    __syncthreads();

    float bj2 = b2[j];
    float pool = 0.f;
    for (int g = 0; g < 2; ++g) {
        int r0 = g * 25;
        float acc[25];
        #pragma unroll
        for (int i = 0; i < 25; i++) acc[i] = bj2;
        for (int k = 0; k < NH; k += 4) {
            float w0 = W2[(k + 0) * NH + j];
            float w1 = W2[(k + 1) * NH + j];
            float w2v = W2[(k + 2) * NH + j];
            float w3v = W2[(k + 3) * NH + j];
            #pragma unroll
            for (int i = 0; i < 25; i++) {
                float4 h4 = *reinterpret_cast<const float4*>(&h1s[r0 + i][k]);
                acc[i] += h4.x * w0 + h4.y * w1 + h4.z * w2v + h4.w * w3v;
            }
        }
        #pragma unroll
        for (int i = 0; i < 25; i++) pool += fmaxf(acc[i], 0.f);
    }

    red[j] = pool * W3[j];
    __syncthreads();
    for (int s = 128; s > 0; s >>= 1) {
        if (j < s) red[j] += red[j + s];
        __syncthreads();
    }
    if (j == 0) {
        float v = red[0] + (half == 0 ? b3[0] : 0.0f);
        atomicAdd(&out[b], v);
    }
}

// ---------------- launch ----------------

extern "C" void kernel_launch(void* const* d_in, const int* in_sizes, int n_in,
                              void* d_out, int out_size, void* d_ws, size_t ws_size,
                              hipStream_t stream) {
    const float* state  = (const float*)d_in[0];
    const int*   ei     = (const int*)d_in[1];
    const float* action = (const float*)d_in[2];
    const float* Wg     = (const float*)d_in[3];
    const float* bg     = (const float*)d_in[4];
    const float* W1     = (const float*)d_in[5];
    const float* b1     = (const float*)d_in[6];
    const float* W2     = (const float*)d_in[7];
    const float* b2     = (const float*)d_in[8];
    const float* W3     = (const float*)d_in[9];
    const float* b3     = (const float*)d_in[10];
    float* out = (float*)d_out;

    char* ws = (char*)d_ws;
    int*   cnt    = (int*)  (ws + 0);
    int*   offs   = (int*)  (ws + 819200);
    int*   cursor = (int*)  (ws + 1638400);
    float* dinv   = (float*)(ws + 2457600);
    int*   bsum   = (int*)  (ws + 3276800);
    int*   csr    = (int*)  (ws + 3278848);
    float* sst    = (float*)(ws + 16386048);
    float* xres   = (float*)(ws + 68814848);

    hipMemsetAsync(cnt, 0, N_NODES * sizeof(int), stream);
    hipMemsetAsync(out, 0, NB * sizeof(float), stream);

    k_count<<<N_EDGES / 256, 256, 0, stream>>>(ei, cnt);
    k_dinv<<<N_NODES / 256, 256, 0, stream>>>(cnt, dinv);
    k_scan1<<<N_NODES / 512, 512, 0, stream>>>(cnt, offs, bsum);
    k_scan2<<<1, 512, 0, stream>>>(bsum);
    k_scan3<<<N_NODES / 512, 512, 0, stream>>>(offs, bsum, cursor);
    k_scatter<<<N_EDGES / 256, 256, 0, stream>>>(ei, cursor, csr);
    k_sstate<<<(N_NODES * NC / 4) / 256, 256, 0, stream>>>(state, dinv, sst);
    k_gcn<<<N_NODES / 4, 256, 0, stream>>>(sst, state, csr, offs, cnt, dinv, Wg, bg, xres);
    k_mlp<<<NB * 2, 256, 0, stream>>>(xres, action, W1, b1, W2, b2, W3, b3, out);
}

// Round 2
// 1720.007 us; speedup vs baseline: 1.1217x; 1.1217x over previous
//
#include <hip/hip_runtime.h>
#include <hip/hip_bf16.h>
#include <cstdint>
#include <cstddef>

#define N_NODES 204800
#define N_EDGES 3276800
#define NB 2048
#define NR 100
#define NC 64
#define NH 256
#define KPAD 192          // 64 + 100 padded to 192 (6 x K32 steps)
#define MCHUNK 51200      // 204800 / 4, divisible by 128 and by 100

typedef __attribute__((ext_vector_type(8))) short short8;
typedef __attribute__((ext_vector_type(4))) float f32x4;

__device__ __forceinline__ void gload16(const void* g, void* l) {
    __builtin_amdgcn_global_load_lds(
        (const __attribute__((address_space(1))) uint32_t*)(g),
        (__attribute__((address_space(3))) uint32_t*)(l), 16, 0, 0);
}

__device__ __forceinline__ ushort f2bf(float v) {
    __hip_bfloat16 h = __float2bfloat16(v);
    return *reinterpret_cast<ushort*>(&h);
}

// ---------------- graph preprocessing ----------------

__global__ void k_count(const int* __restrict__ ei, int* __restrict__ cnt) {
    int e = blockIdx.x * 256 + threadIdx.x;
    atomicAdd(&cnt[ei[N_EDGES + e]], 1);
}

__global__ void k_dinv(const int* __restrict__ cnt, float* __restrict__ dinv) {
    int i = blockIdx.x * 256 + threadIdx.x;
    dinv[i] = rsqrtf((float)(cnt[i] + 1));   // +1 self loop
}

__global__ void k_scan1(const int* __restrict__ cnt, int* __restrict__ offs,
                        int* __restrict__ bsum) {
    __shared__ int tmp[512];
    int t = threadIdx.x;
    int idx = blockIdx.x * 512 + t;
    int v = cnt[idx];
    tmp[t] = v;
    __syncthreads();
    for (int off = 1; off < 512; off <<= 1) {
        int x = 0;
        if (t >= off) x = tmp[t - off];
        __syncthreads();
        tmp[t] += x;
        __syncthreads();
    }
    offs[idx] = tmp[t] - v;                 // exclusive
    if (t == 511) bsum[blockIdx.x] = tmp[511];
}

__global__ void k_scan2(int* __restrict__ bsum) {
    __shared__ int tmp[512];
    int t = threadIdx.x;
    int v = (t < 400) ? bsum[t] : 0;
    tmp[t] = v;
    __syncthreads();
    for (int off = 1; off < 512; off <<= 1) {
        int x = 0;
        if (t >= off) x = tmp[t - off];
        __syncthreads();
        tmp[t] += x;
        __syncthreads();
    }
    if (t < 400) bsum[t] = tmp[t] - v;      // exclusive block bases
}

__global__ void k_scan3(int* __restrict__ offs, const int* __restrict__ bsum,
                        int* __restrict__ cursor) {
    int t = threadIdx.x;
    int idx = blockIdx.x * 512 + t;
    int o = offs[idx] + bsum[blockIdx.x];
    offs[idx] = o;
    cursor[idx] = o;
}

__global__ void k_scatter(const int* __restrict__ ei, int* __restrict__ cursor,
                          int* __restrict__ csr) {
    int e = blockIdx.x * 256 + threadIdx.x;
    int s = ei[e];
    int d = ei[N_EDGES + e];
    int p = atomicAdd(&cursor[d], 1);
    csr[p] = s;
}

// ---------------- GCN gather + 64x64 GEMM + relu + residual ----------------
// one wave per node row; lane = channel. dinv[src] folded in (no sstate pass).
__global__ __launch_bounds__(256) void k_gcn(
    const float* __restrict__ state,
    const int* __restrict__ csr, const int* __restrict__ offs,
    const int* __restrict__ cnt, const float* __restrict__ dinv,
    const float* __restrict__ Wg, const float* __restrict__ bg,
    float* __restrict__ xres) {
    __shared__ float Wl[64 * 64];
    __shared__ float av[4][64];
    int tid = threadIdx.x;
    for (int i = tid; i < 1024; i += 256)
        reinterpret_cast<float4*>(Wl)[i] = reinterpret_cast<const float4*>(Wg)[i];

    int wave = tid >> 6, lane = tid & 63;
    int row = blockIdx.x * 4 + wave;

    float di = dinv[row];
    float st = state[(size_t)row * 64 + lane];
    float a0 = st * di;                           // self loop
    float a1 = 0.f, a2 = 0.f, a3 = 0.f;
    int s0 = offs[row], c = cnt[row];
    int e = 0;
    for (; e + 4 <= c; e += 4) {
        int sa = csr[s0 + e + 0];
        int sb = csr[s0 + e + 1];
        int sc = csr[s0 + e + 2];
        int sd = csr[s0 + e + 3];
        a0 += state[(size_t)sa * 64 + lane] * dinv[sa];
        a1 += state[(size_t)sb * 64 + lane] * dinv[sb];
        a2 += state[(size_t)sc * 64 + lane] * dinv[sc];
        a3 += state[(size_t)sd * 64 + lane] * dinv[sd];
    }
    for (; e < c; ++e) {
        int s = csr[s0 + e];
        a0 += state[(size_t)s * 64 + lane] * dinv[s];
    }
    float a = ((a0 + a1) + (a2 + a3)) * di;

    __syncthreads();            // Wl ready
    av[wave][lane] = a;
    __syncthreads();            // av ready

    float r = bg[lane];
    #pragma unroll
    for (int c4 = 0; c4 < 64; c4 += 4) {
        float4 a4 = *reinterpret_cast<const float4*>(&av[wave][c4]);
        r += a4.x * Wl[(c4 + 0) * 64 + lane];
        r += a4.y * Wl[(c4 + 1) * 64 + lane];
        r += a4.z * Wl[(c4 + 2) * 64 + lane];
        r += a4.w * Wl[(c4 + 3) * 64 + lane];
    }
    xres[(size_t)row * 64 + lane] = fmaxf(r, 0.f) + st;
}

// ---------------- pack kernels ----------------

// A[lr][0:64]=xres, [64:164]=action, [164:192]=0 ; bf16, one chunk of rows
__global__ __launch_bounds__(256) void k_packA(
    const float* __restrict__ xres, const float* __restrict__ action,
    ushort* __restrict__ Ap, int grow0) {
    int tid = threadIdx.x;
    int w = tid >> 6, lane = tid & 63;
    int lr = blockIdx.x * 4 + w;
    int gr = grow0 + lr;
    int b = gr / 100, r = gr % 100;
    const float* ab = action + (size_t)b * 10000 + (size_t)r * 100;
    float v0 = xres[(size_t)gr * 64 + lane];
    float v1 = ab[lane];
    float v2 = (lane < 36) ? ab[64 + lane] : 0.f;
    ushort* row = Ap + (size_t)lr * KPAD;
    row[lane] = f2bf(v0);
    row[64 + lane] = f2bf(v1);
    row[128 + lane] = f2bf(v2);
}

// W1t[j][k] = W1[k][j] (k<164, else 0), W2t[j][k] = W2[k][j]; bf16
__global__ void k_packW(const float* __restrict__ W1, const float* __restrict__ W2,
                        ushort* __restrict__ W1t, ushort* __restrict__ W2t) {
    int t = blockIdx.x * 256 + threadIdx.x;
    if (t < 256 * KPAD) {
        int j = t / KPAD, k = t % KPAD;
        W1t[t] = (k < NC + NR) ? f2bf(W1[(size_t)k * NH + j]) : (ushort)0;
    } else {
        int t2 = t - 256 * KPAD;
        if (t2 < 256 * 256) {
            int j = t2 / 256, k = t2 % 256;
            W2t[t2] = f2bf(W2[(size_t)k * NH + j]);
        }
    }
}

// ---------------- MFMA GEMMs (m97-style 128x128 tile, BK=32) ----------------

// H1 = relu(Ap @ W1t^T + b1), bf16 out.  Ap:[MCHUNK][192], W1t:[256][192]
__global__ __launch_bounds__(256) void k_gemm1(
    const ushort* __restrict__ Ap, const ushort* __restrict__ W1t,
    const float* __restrict__ b1, ushort* __restrict__ H1) {
    __shared__ __align__(16) ushort Asm[128 * 32];
    __shared__ __align__(16) ushort Bsm[128 * 32];
    int tid = threadIdx.x;
    int w = tid >> 6, lane = tid & 63;
    int m0 = (blockIdx.x >> 1) * 128;
    int n0 = (blockIdx.x & 1) * 128;
    int wm = w >> 1, wn = w & 1;
    int srow = lane >> 2, seg = lane & 3;

    f32x4 acc[4][4] = {};

    for (int kt = 0; kt < 6; ++kt) {
        int k0 = kt * 32;
        #pragma unroll
        for (int i = 0; i < 2; ++i) {
            int rr = (w * 2 + i) * 16 + srow;
            gload16(Ap + (size_t)(m0 + rr) * KPAD + k0 + seg * 8,
                    (char*)Asm + (w * 2 + i) * 1024 + lane * 16);
            gload16(W1t + (size_t)(n0 + rr) * KPAD + k0 + seg * 8,
                    (char*)Bsm + (w * 2 + i) * 1024 + lane * 16);
        }
        __syncthreads();
        short8 af[4], bfr[4];
        #pragma unroll
        for (int mt = 0; mt < 4; ++mt)
            af[mt] = *(const short8*)((const char*)Asm +
                     (wm * 64 + mt * 16 + (lane & 15)) * 64 + (lane >> 4) * 16);
        #pragma unroll
        for (int nt = 0; nt < 4; ++nt)
            bfr[nt] = *(const short8*)((const char*)Bsm +
                      (wn * 64 + nt * 16 + (lane & 15)) * 64 + (lane >> 4) * 16);
        #pragma unroll
        for (int mt = 0; mt < 4; ++mt)
            #pragma unroll
            for (int nt = 0; nt < 4; ++nt)
                acc[mt][nt] = __builtin_amdgcn_mfma_f32_16x16x32_bf16(
                    af[mt], bfr[nt], acc[mt][nt], 0, 0, 0);
        __syncthreads();
    }

    #pragma unroll
    for (int nt = 0; nt < 4; ++nt) {
        int col = n0 + wn * 64 + nt * 16 + (lane & 15);
        float bias = b1[col];
        #pragma unroll
        for (int mt = 0; mt < 4; ++mt) {
            #pragma unroll
            for (int r = 0; r < 4; ++r) {
                int row = m0 + wm * 64 + mt * 16 + (lane >> 4) * 4 + r;
                float v = acc[mt][nt][r] + bias;
                H1[(size_t)row * 256 + col] = f2bf(fmaxf(v, 0.f));
            }
        }
    }
}

// out[g] += sum_rows sum_j relu(H1 @ W2t^T + b2) * W3[j]
__global__ __launch_bounds__(256) void k_gemm2(
    const ushort* __restrict__ H1, const ushort* __restrict__ W2t,
    const float* __restrict__ b2, const float* __restrict__ W3,
    float* __restrict__ out, int grow0) {
    __shared__ __align__(16) ushort Asm[128 * 32];
    __shared__ __align__(16) ushort Bsm[128 * 32];
    int tid = threadIdx.x;
    int w = tid >> 6, lane = tid & 63;
    int m0 = (blockIdx.x >> 1) * 128;
    int n0 = (blockIdx.x & 1) * 128;
    int wm = w >> 1, wn = w & 1;
    int srow = lane >> 2, seg = lane & 3;

    f32x4 acc[4][4] = {};

    for (int kt = 0; kt < 8; ++kt) {
        int k0 = kt * 32;
        #pragma unroll
        for (int i = 0; i < 2; ++i) {
            int rr = (w * 2 + i) * 16 + srow;
            gload16(H1 + (size_t)(m0 + rr) * 256 + k0 + seg * 8,
                    (char*)Asm + (w * 2 + i) * 1024 + lane * 16);
            gload16(W2t + (size_t)(n0 + rr) * 256 + k0 + seg * 8,
                    (char*)Bsm + (w * 2 + i) * 1024 + lane * 16);
        }
        __syncthreads();
        short8 af[4], bfr[4];
        #pragma unroll
        for (int mt = 0; mt < 4; ++mt)
            af[mt] = *(const short8*)((const char*)Asm +
                     (wm * 64 + mt * 16 + (lane & 15)) * 64 + (lane >> 4) * 16);
        #pragma unroll
        for (int nt = 0; nt < 4; ++nt)
            bfr[nt] = *(const short8*)((const char*)Bsm +
                      (wn * 64 + nt * 16 + (lane & 15)) * 64 + (lane >> 4) * 16);
        #pragma unroll
        for (int mt = 0; mt < 4; ++mt)
            #pragma unroll
            for (int nt = 0; nt < 4; ++nt)
                acc[mt][nt] = __builtin_amdgcn_mfma_f32_16x16x32_bf16(
                    af[mt], bfr[nt], acc[mt][nt], 0, 0, 0);
        __syncthreads();
    }

    float p[4][4];
    #pragma unroll
    for (int mt = 0; mt < 4; ++mt)
        #pragma unroll
        for (int r = 0; r < 4; ++r) p[mt][r] = 0.f;

    #pragma unroll
    for (int nt = 0; nt < 4; ++nt) {
        int col = n0 + wn * 64 + nt * 16 + (lane & 15);
        float bias = b2[col];
        float w3v = W3[col];
        #pragma unroll
        for (int mt = 0; mt < 4; ++mt) {
            #pragma unroll
            for (int r = 0; r < 4; ++r) {
                float v = fmaxf(acc[mt][nt][r] + bias, 0.f);
                p[mt][r] += v * w3v;
            }
        }
    }

    #pragma unroll
    for (int mt = 0; mt < 4; ++mt) {
        #pragma unroll
        for (int r = 0; r < 4; ++r) {
            float v = p[mt][r];
            v += __shfl_xor(v, 1);
            v += __shfl_xor(v, 2);
            v += __shfl_xor(v, 4);
            v += __shfl_xor(v, 8);
            if ((lane & 15) == 0) {
                int row = grow0 + m0 + wm * 64 + mt * 16 + (lane >> 4) * 4 + r;
                atomicAdd(&out[row / 100], v);
            }
        }
    }
}

__global__ void k_init_out(float* __restrict__ out, const float* __restrict__ b3) {
    int i = blockIdx.x * 256 + threadIdx.x;
    out[i] = b3[0];
}

// ---------------- launch ----------------

extern "C" void kernel_launch(void* const* d_in, const int* in_sizes, int n_in,
                              void* d_out, int out_size, void* d_ws, size_t ws_size,
                              hipStream_t stream) {
    const float* state  = (const float*)d_in[0];
    const int*   ei     = (const int*)d_in[1];
    const float* action = (const float*)d_in[2];
    const float* Wg     = (const float*)d_in[3];
    const float* bg     = (const float*)d_in[4];
    const float* W1     = (const float*)d_in[5];
    const float* b1     = (const float*)d_in[6];
    const float* W2     = (const float*)d_in[7];
    const float* b2     = (const float*)d_in[8];
    const float* W3     = (const float*)d_in[9];
    const float* b3     = (const float*)d_in[10];
    float* out = (float*)d_out;

    char* ws = (char*)d_ws;
    // live ranges:  xres: [gcn, packA(last)] ; prep: [start, gcn] ;
    // Ap(chunk): [packA(c), gemm1(c)] overlays prep ; H1(chunk): [gemm1(c), gemm2(c)]
    float* xres   = (float*)(ws + 0);                      // 52,428,800 B
    char*  prep   = ws + 52428800;
    int*   cnt    = (int*)  (prep + 0);
    int*   offs   = (int*)  (prep + 819200);
    int*   cursor = (int*)  (prep + 1638400);
    float* dinv   = (float*)(prep + 2457600);
    int*   bsum   = (int*)  (prep + 3276800);
    int*   csr    = (int*)  (prep + 3280896);              // ends prep+16,388,096
    ushort* Ap    = (ushort*)(ws + 52428800);              // 19,660,800 B (overlays prep)
    ushort* H1    = (ushort*)(ws + 72089600);              // 26,214,400 B
    ushort* W1t   = (ushort*)(ws + 98304000);              // 98,304 B
    ushort* W2t   = (ushort*)(ws + 98402304);              // 131,072 B -> end 98,533,376

    hipMemsetAsync(cnt, 0, N_NODES * sizeof(int), stream);
    k_init_out<<<NB / 256, 256, 0, stream>>>(out, b3);

    k_count<<<N_EDGES / 256, 256, 0, stream>>>(ei, cnt);
    k_dinv<<<N_NODES / 256, 256, 0, stream>>>(cnt, dinv);
    k_scan1<<<N_NODES / 512, 512, 0, stream>>>(cnt, offs, bsum);
    k_scan2<<<1, 512, 0, stream>>>(bsum);
    k_scan3<<<N_NODES / 512, 512, 0, stream>>>(offs, bsum, cursor);
    k_scatter<<<N_EDGES / 256, 256, 0, stream>>>(ei, cursor, csr);
    k_gcn<<<N_NODES / 4, 256, 0, stream>>>(state, csr, offs, cnt, dinv, Wg, bg, xres);
    k_packW<<<(256 * KPAD + 256 * 256 + 255) / 256, 256, 0, stream>>>(W1, W2, W1t, W2t);

    for (int c = 0; c < 4; ++c) {
        int grow0 = c * MCHUNK;
        k_packA<<<MCHUNK / 4, 256, 0, stream>>>(xres, action, Ap, grow0);
        k_gemm1<<<(MCHUNK / 128) * 2, 256, 0, stream>>>(Ap, W1t, b1, H1);
        k_gemm2<<<(MCHUNK / 128) * 2, 256, 0, stream>>>(H1, W2t, b2, W3, out, grow0);
    }
}